// Round 4
// baseline (505.545 us; speedup 1.0000x reference)
//
#include <hip/hip_runtime.h>

#define DIMC 2048
#define NSEQ 2048
#define NBATCH 2
#define NH 32
#define DH 64
#define BHEADS (NBATCH*NH)      // 64
#define MROWS (NBATCH*NSEQ)     // 4096
#define NQKV (3*DIMC)           // 6144

typedef __attribute__((ext_vector_type(8))) short short8;
typedef __attribute__((ext_vector_type(4))) float f32x4;
typedef __attribute__((ext_vector_type(4))) unsigned int uint4v;
typedef __attribute__((ext_vector_type(2))) unsigned int u32x2;

static __device__ __forceinline__ unsigned short f2bf(float f) {
  union { float f; unsigned int u; } v; v.f = f;
  unsigned int r = (v.u + 0x7FFFu + ((v.u >> 16) & 1u)) >> 16;
  return (unsigned short)r;
}

static __device__ __forceinline__ unsigned int cvt_pk_bf16(float lo, float hi) {
  unsigned int r;
  asm("v_cvt_pk_bf16_f32 %0, %1, %2" : "=v"(r) : "v"(lo), "v"(hi));
  return r;
}

#define BAR()    __builtin_amdgcn_s_barrier()
#define LGKM0()  asm volatile("s_waitcnt lgkmcnt(0)" ::: "memory")
#define LGKM8()  asm volatile("s_waitcnt lgkmcnt(8)" ::: "memory")
#define VM(n)    asm volatile("s_waitcnt vmcnt(" #n ")" ::: "memory")

// ---------------- fp32 -> bf16 convert (vectorized, grid-stride) ------------
__global__ __launch_bounds__(256) void cvt_bf16(const float* __restrict__ in,
                                                unsigned short* __restrict__ out,
                                                int n8) {
  int i = blockIdx.x * blockDim.x + threadIdx.x;
  int stride = gridDim.x * blockDim.x;
  for (; i < n8; i += stride) {
    const float4* p = (const float4*)in + (size_t)i * 2;
    float4 a = p[0], b = p[1];
    union { unsigned short u[8]; uint4v v; } o;
    o.u[0] = f2bf(a.x); o.u[1] = f2bf(a.y); o.u[2] = f2bf(a.z); o.u[3] = f2bf(a.w);
    o.u[4] = f2bf(b.x); o.u[5] = f2bf(b.y); o.u[6] = f2bf(b.z); o.u[7] = f2bf(b.w);
    *((uint4v*)out + i) = o.v;
  }
}

// ---------------- cos/sin table --------------------------------------------
__global__ __launch_bounds__(256) void build_cs(const float* __restrict__ freqs,
                                                float2* __restrict__ cs, int n) {
  int i = blockIdx.x * blockDim.x + threadIdx.x;
  if (i < n) { float f = freqs[i]; cs[i] = make_float2(cosf(f), sinf(f)); }
}

// ---------------- 256x256 8-phase GEMM: C = A[M,K] * B[N,K]^T ---------------
// 512 thr (8 waves 2Mx4N), BK=64, 128KB dbuf LDS, st_16x32 swizzle,
// counted vmcnt(4), setprio around MFMA, XCD-swizzled blockIdx.
// WAR-safe staging: each STAGE targets a region whose last ds_read was in an
// earlier phase (readers retire reads at lgkmcnt(0) before that phase's 2nd
// barrier). buf0-A last read ph0, buf0-B ph1, buf1-A ph4, buf1-B ph5.
#define QSCALE 0.18033688011112042f   // (1/8) * log2(e)

template<int EPI>
__global__ __launch_bounds__(512, 2) void gemm256(
    const unsigned short* __restrict__ A,
    const unsigned short* __restrict__ Bm,
    int Kdim, int Ncols,
    float* __restrict__ Cout,
    unsigned short* __restrict__ qo, unsigned short* __restrict__ ko,
    unsigned short* __restrict__ vo, const float2* __restrict__ cs)
{
  extern __shared__ char Lds[];   // 131072 bytes
  const int t = threadIdx.x;
  const int w = t >> 6, lane = t & 63, lr = lane & 15, g = lane >> 4;
  const int wm = w >> 2, wn = w & 3;
  const int gx = (g * 16) ^ ((lr & 4) << 3);       // swizzled in-row byte offset

  // XCD-aware bijective swizzle (grid counts are multiples of 8)
  const int nx = gridDim.x;
  int orig = blockIdx.y * nx + blockIdx.x;
  int cpx = (nx * gridDim.y) >> 3;
  int id = (orig & 7) * cpx + (orig >> 3);
  const int m0 = (id / nx) * 256;
  const int n0 = (id % nx) * 256;

  // staging source bases (pre-swizzled global addresses; LDS dest stays linear)
  const int lp = lane ^ ((lane & 32) >> 4);        // flip bit1 when bit5 set
  const unsigned short* sbase[2][2][2];
  #pragma unroll
  for (int c = 0; c < 2; c++) {
    int srow = w * 16 + c * 8 + (lp >> 3);
    int scol = (lp & 7) * 8;
    sbase[0][0][c] = A  + (size_t)(m0 + srow) * Kdim + scol;
    sbase[0][1][c] = A  + (size_t)(m0 + 128 + srow) * Kdim + scol;
    sbase[1][0][c] = Bm + (size_t)(n0 + srow) * Kdim + scol;
    sbase[1][1][c] = Bm + (size_t)(n0 + 128 + srow) * Kdim + scol;
  }

  auto STAGE = [&](int op, int half, int buf, int T) {
    const unsigned short* s0 = sbase[op][half][0] + (size_t)T * 64;
    const unsigned short* s1 = sbase[op][half][1] + (size_t)T * 64;
    char* d = Lds + buf * 65536 + op * 32768 + half * 16384 + w * 2048;
    __builtin_amdgcn_global_load_lds(
        (const __attribute__((address_space(1))) void*)s0,
        (__attribute__((address_space(3))) void*)d, 16, 0, 0);
    __builtin_amdgcn_global_load_lds(
        (const __attribute__((address_space(1))) void*)s1,
        (__attribute__((address_space(3))) void*)(d + 1024), 16, 0, 0);
  };

  short8 A0r[2][4], A1r[2][4], B0r[2][2], B1r[2][2];  // [ks][frag]

  auto LDA = [&](short8 (&dst)[2][4], int bufb, int mlo) {
    const char* bp = Lds + bufb + wm * 16384 + (mlo * 16 + lr) * 128 + gx;
    #pragma unroll
    for (int ks = 0; ks < 2; ks++)
      #pragma unroll
      for (int mm = 0; mm < 4; mm++)
        dst[ks][mm] = *(const short8*)(bp + mm * 2048 + ks * 64);
  };
  auto LDB = [&](short8 (&dst)[2][2], int bufb, int nlo) {
    const char* bp = Lds + bufb + 32768 + (wn >> 1) * 16384 + (wn & 1) * 8192
                     + (nlo * 16 + lr) * 128 + gx;
    #pragma unroll
    for (int ks = 0; ks < 2; ks++)
      #pragma unroll
      for (int nn = 0; nn < 2; nn++)
        dst[ks][nn] = *(const short8*)(bp + nn * 2048 + ks * 64);
  };

  f32x4 acc[8][4];
  f32x4 zero = {0.0f, 0.0f, 0.0f, 0.0f};
  #pragma unroll
  for (int i = 0; i < 8; i++)
    #pragma unroll
    for (int j = 0; j < 4; j++) acc[i][j] = zero;

  auto MM = [&](short8 (&Af)[2][4], short8 (&Bf)[2][2], int mq, int nq) {
    __builtin_amdgcn_s_setprio(1);
    #pragma unroll
    for (int mm = 0; mm < 4; mm++)
      #pragma unroll
      for (int nn = 0; nn < 2; nn++)
        #pragma unroll
        for (int ks = 0; ks < 2; ks++)
          acc[mq * 4 + mm][nq * 2 + nn] = __builtin_amdgcn_mfma_f32_16x16x32_bf16(
              Af[ks][mm], Bf[ks][nn], acc[mq * 4 + mm][nq * 2 + nn], 0, 0, 0);
    __builtin_amdgcn_s_setprio(0);
  };

  // ---- prologue: tile0 complete + tile1 {Ah0,Bh0,Ah1}; wait tile 0 ----
  STAGE(0,0,0, 0); STAGE(1,0,0, 0); STAGE(0,1,0, 0); STAGE(1,1,0, 0);
  STAGE(0,0,1, 1); STAGE(1,0,1, 1); STAGE(0,1,1, 1);
  VM(6);            // 14 issued; wait -> tile 0's 8 loads landed
  BAR();
  LDA(A0r, 0, 0); LDB(B0r, 0, 0);

  const int NIT = Kdim >> 7;   // 2 K-tiles (BK=64) per iteration
  for (int i = 0; i < NIT; i++) {
    const bool more = (i < NIT - 1);
    const int Tc  = 2 * i + 1;   // current odd tile (buf1): finish its Bh1
    const int Tn0 = 2 * i + 2;   // next even tile -> buf0
    const int Tn1 = 2 * i + 3;   // next odd tile  -> buf1
    // ph0: q(0,0) even tile; stage Bh1@buf1 for tile Tc (buf1-B last read ph5-prev)
    LDA(A1r, 0, 4);
    STAGE(1,1,1, Tc);
    BAR(); LGKM0(); MM(A0r, B0r, 0, 0); BAR();
    // ph1: stage Ah0@buf0 (buf0-A last read ph0)
    LDB(B1r, 0, 2);
    if (more) STAGE(0,0,0, Tn0);
    BAR(); LGKM0(); MM(A1r, B0r, 1, 0); BAR();
    // ph2: stage Bh0@buf0 (buf0-B last read ph1); guard buf1 tile Tc before ph3
    if (more) STAGE(1,0,0, Tn0);
    BAR(); LGKM0(); MM(A1r, B1r, 1, 1);
    if (more) { VM(4); } else { VM(0); }
    BAR();
    // ph3: read buf1 (tile Tc); stage Ah1@buf0
    LDA(A1r, 65536, 0); LDB(B0r, 65536, 0);
    if (more) STAGE(0,1,0, Tn0);
    LGKM8();
    BAR(); LGKM0(); MM(A0r, B1r, 0, 1); BAR();
    // ph4: stage Bh1@buf0 (tile Tn0 complete)
    LDA(A0r, 65536, 4);
    if (more) STAGE(1,1,0, Tn0);
    BAR(); LGKM0(); MM(A1r, B0r, 0, 0); BAR();
    // ph5: stage Ah0@buf1 (buf1-A last read ph4)
    LDB(B1r, 65536, 2);
    if (more) STAGE(0,0,1, Tn1);
    BAR(); LGKM0(); MM(A0r, B0r, 1, 0); BAR();
    // ph6: stage Bh0@buf1 (buf1-B last read ph5); guard buf0 tile Tn0 before ph7
    if (more) STAGE(1,0,1, Tn1);
    BAR(); LGKM0(); MM(A0r, B1r, 1, 1);
    if (more) VM(4);
    BAR();
    // ph7: prefetch-read buf0 (tile Tn0); stage Ah1@buf1
    if (more) {
      LDA(A0r, 0, 0); LDB(B0r, 0, 0);
      STAGE(0,1,1, Tn1);
      LGKM8();
    }
    BAR(); LGKM0(); MM(A1r, B1r, 0, 1); BAR();
  }

  // ---- epilogue ----
  if (EPI == 0) {
    #pragma unroll
    for (int m = 0; m < 8; m++) {
      #pragma unroll
      for (int r = 0; r < 4; r++) {
        int row = m0 + wm * 128 + m * 16 + g * 4 + r;
        #pragma unroll
        for (int n = 0; n < 4; n++)
          Cout[(size_t)row * Ncols + (n0 + wn * 64 + n * 16 + lr)] = acc[m][n][r];
      }
    }
  } else {
    const int which = n0 >> 11;
    const int head = ((n0 & 2047) + wn * 64) >> 6;
    #pragma unroll
    for (int m = 0; m < 8; m++) {
      #pragma unroll
      for (int r = 0; r < 4; r++) {
        int row = m0 + wm * 128 + m * 16 + g * 4 + r;
        int b = row >> 11, ntok = row & 2047;
        size_t obase = ((size_t)(b * NH + head) * NSEQ + ntok) * DH;
        #pragma unroll
        for (int n = 0; n < 4; n++) {
          int d = n * 16 + lr;
          float val = acc[m][n][r];
          if (which == 2) {
            vo[obase + d] = f2bf(val);
          } else {
            float other = acc[m][n ^ 2][r];
            float2 c2 = cs[ntok * DH + d];
            float rot = (d < 32) ? (val * c2.x - other * c2.y)
                                 : (val * c2.x + other * c2.y);
            if (which == 0) qo[obase + d] = f2bf(rot * QSCALE);
            else            ko[obase + d] = f2bf(rot);
          }
        }
      }
    }
  }
}

// ---------------- flash attention: 4 waves x 32 q, KVBLK=64 -----------------
__global__ __launch_bounds__(256, 4) void attn_fa(
    const unsigned short* __restrict__ qb,
    const unsigned short* __restrict__ kb,
    const unsigned short* __restrict__ vb,
    unsigned short* __restrict__ aob)
{
  __shared__ __align__(16) unsigned short Kl[64 * 64];      // linear, XOR-swizzled content
  __shared__ __align__(16) unsigned short Vt[64 * 72];      // [d][k + pad8]
  __shared__ __align__(16) unsigned short Pl[4][32 * 72];   // per-wave [q][k + pad8]

  const int t = threadIdx.x;
  const int w = t >> 6, lane = t & 63, lr = lane & 15, g = lane >> 4;
  const int bh = blockIdx.y;
  const int q0 = blockIdx.x * 128 + w * 32;
  const size_t hbase = (size_t)bh * NSEQ * DH;

  short8 qf[2][2];
  #pragma unroll
  for (int qt = 0; qt < 2; qt++)
    #pragma unroll
    for (int hf = 0; hf < 2; hf++)
      qf[qt][hf] = *(const short8*)(qb + hbase + (size_t)(q0 + qt * 16 + lr) * DH + hf * 32 + g * 8);

  f32x4 zero = {0.0f, 0.0f, 0.0f, 0.0f};
  f32x4 oacc[2][4];
  #pragma unroll
  for (int qt = 0; qt < 2; qt++)
    #pragma unroll
    for (int dv = 0; dv < 4; dv++) oacc[qt][dv] = zero;
  float mrun[2] = {-1e30f, -1e30f};
  float lrun[2] = {0.0f, 0.0f};

  int kro[2], kdo_[2];
  #pragma unroll
  for (int c = 0; c < 2; c++) {
    int b = w * 2048 + c * 1024 + lane * 16;
    int row = b >> 7;
    int off = b ^ ((row & 7) << 4);
    kro[c] = row;
    kdo_[c] = (off >> 1) & 63;
  }
  const int vr0 = (t & 31) * 2;
  const int vhv = (t >> 5) * 8;

  unsigned short* prow0 = &Pl[w][lr * 72];
  unsigned short* prow1 = &Pl[w][(16 + lr) * 72];

  for (int kv0 = 0; kv0 < NSEQ; kv0 += 64) {
    __syncthreads();
    #pragma unroll
    for (int c = 0; c < 2; c++) {
      const unsigned short* src = kb + hbase + (size_t)(kv0 + kro[c]) * DH + kdo_[c];
      __builtin_amdgcn_global_load_lds(
          (const __attribute__((address_space(1))) void*)src,
          (__attribute__((address_space(3))) void*)(Kl + w * 1024 + c * 512), 16, 0, 0);
    }
    {
      const unsigned short* s0 = vb + hbase + (size_t)(kv0 + vr0) * DH + vhv;
      short8 v0 = *(const short8*)(s0);
      short8 v1 = *(const short8*)(s0 + DH);
      #pragma unroll
      for (int j = 0; j < 8; j++) {
        unsigned int p = ((unsigned short)v0[j]) | (((unsigned int)(unsigned short)v1[j]) << 16);
        *(unsigned int*)&Vt[(vhv + j) * 72 + vr0] = p;
      }
    }
    __syncthreads();

    f32x4 s[2][4];
    #pragma unroll
    for (int kt = 0; kt < 4; kt++) {
      int row = kt * 16 + lr;
      int sw = (row & 7) << 4;
      int byteA = (row * 128 + g * 16) ^ sw;
      int byteB = (row * 128 + 64 + g * 16) ^ sw;
      short8 kA = *(const short8*)((const char*)Kl + byteA);
      short8 kB = *(const short8*)((const char*)Kl + byteB);
      #pragma unroll
      for (int qt = 0; qt < 2; qt++) {
        f32x4 a0 = __builtin_amdgcn_mfma_f32_16x16x32_bf16(kA, qf[qt][0], zero, 0, 0, 0);
        s[qt][kt] = __builtin_amdgcn_mfma_f32_16x16x32_bf16(kB, qf[qt][1], a0, 0, 0, 0);
      }
    }

    float nm[2];
    #pragma unroll
    for (int qt = 0; qt < 2; qt++) {
      f32x4 m01 = s[qt][0];
      #pragma unroll
      for (int kt = 1; kt < 4; kt++) {
        f32x4 sv = s[qt][kt];
        m01[0] = fmaxf(m01[0], sv[0]); m01[1] = fmaxf(m01[1], sv[1]);
        m01[2] = fmaxf(m01[2], sv[2]); m01[3] = fmaxf(m01[3], sv[3]);
      }
      float v = fmaxf(fmaxf(m01[0], m01[1]), fmaxf(m01[2], m01[3]));
      v = fmaxf(v, __shfl_xor(v, 16));
      v = fmaxf(v, __shfl_xor(v, 32));
      nm[qt] = v;
    }

    if (!__all(fmaxf(nm[0] - mrun[0], nm[1] - mrun[1]) <= 8.0f)) {
      const int sb = (lane & 48) + ((lane & 48) >> 2);
      #pragma unroll
      for (int qt = 0; qt < 2; qt++) {
        float m2 = fmaxf(mrun[qt], nm[qt]);
        float cc = exp2f(mrun[qt] - m2);
        mrun[qt] = m2;
        lrun[qt] *= cc;
        float c0r = __shfl(cc, sb + 0);
        float c1r = __shfl(cc, sb + 1);
        float c2r = __shfl(cc, sb + 2);
        float c3r = __shfl(cc, sb + 3);
        #pragma unroll
        for (int dv = 0; dv < 4; dv++) {
          f32x4 a = oacc[qt][dv];
          a[0] *= c0r; a[1] *= c1r; a[2] *= c2r; a[3] *= c3r;
          oacc[qt][dv] = a;
        }
      }
    }

    #pragma unroll
    for (int qt = 0; qt < 2; qt++) {
      float mq = mrun[qt];
      float ls = 0.0f;
      unsigned short* prow = qt ? prow1 : prow0;
      #pragma unroll
      for (int kt = 0; kt < 4; kt++) {
        f32x4 sv = s[qt][kt];
        float p0 = exp2f(sv[0] - mq), p1 = exp2f(sv[1] - mq);
        float p2 = exp2f(sv[2] - mq), p3 = exp2f(sv[3] - mq);
        ls += (p0 + p1) + (p2 + p3);
        u32x2 uu;
        uu.x = cvt_pk_bf16(p0, p1);
        uu.y = cvt_pk_bf16(p2, p3);
        *(u32x2*)(prow + kt * 16 + g * 4) = uu;
      }
      ls += __shfl_xor(ls, 16);
      ls += __shfl_xor(ls, 32);
      lrun[qt] += ls;
    }

    #pragma unroll
    for (int c0 = 0; c0 < 2; c0++) {
      short8 pa0 = *(const short8*)(prow0 + c0 * 32 + g * 8);
      short8 pa1 = *(const short8*)(prow1 + c0 * 32 + g * 8);
      #pragma unroll
      for (int dv = 0; dv < 4; dv++) {
        short8 vf = *(const short8*)&Vt[(dv * 16 + lr) * 72 + c0 * 32 + g * 8];
        oacc[0][dv] = __builtin_amdgcn_mfma_f32_16x16x32_bf16(pa0, vf, oacc[0][dv], 0, 0, 0);
        oacc[1][dv] = __builtin_amdgcn_mfma_f32_16x16x32_bf16(pa1, vf, oacc[1][dv], 0, 0, 0);
      }
    }
  }

  const int b = bh >> 5, h = bh & 31;
  const int sb = (lane & 48) + ((lane & 48) >> 2);
  #pragma unroll
  for (int qt = 0; qt < 2; qt++) {
    float inv = 1.0f / lrun[qt];
    float ir[4];
    ir[0] = __shfl(inv, sb + 0);
    ir[1] = __shfl(inv, sb + 1);
    ir[2] = __shfl(inv, sb + 2);
    ir[3] = __shfl(inv, sb + 3);
    #pragma unroll
    for (int r = 0; r < 4; r++) {
      int ntok = q0 + qt * 16 + g * 4 + r;
      size_t ob = ((size_t)(b * NSEQ + ntok)) * DIMC + h * DH;
      #pragma unroll
      for (int dv = 0; dv < 4; dv++)
        aob[ob + dv * 16 + lr] = f2bf(oacc[qt][dv][r] * ir[r]);
    }
  }
}

// ---------------------------------------------------------------------------
extern "C" void kernel_launch(void* const* d_in, const int* in_sizes, int n_in,
                              void* d_out, int out_size, void* d_ws, size_t ws_size,
                              hipStream_t stream) {
  const float* x     = (const float*)d_in[0];
  const float* freqs = (const float*)d_in[1];
  const float* Wqkv  = (const float*)d_in[2];
  const float* Wout  = (const float*)d_in[3];
  float* out = (float*)d_out;

  char* ws = (char*)d_ws;
  size_t off = 0;
  auto alloc = [&](size_t bytes) {
    void* p = ws + off;
    off += (bytes + 255) & ~(size_t)255;
    return p;
  };
  unsigned short* xb    = (unsigned short*)alloc((size_t)MROWS * DIMC * 2);
  unsigned short* wqkvb = (unsigned short*)alloc((size_t)NQKV * DIMC * 2);
  unsigned short* woutb = (unsigned short*)alloc((size_t)DIMC * DIMC * 2);
  unsigned short* qbuf  = (unsigned short*)alloc((size_t)BHEADS * NSEQ * DH * 2);
  unsigned short* kbuf  = (unsigned short*)alloc((size_t)BHEADS * NSEQ * DH * 2);
  unsigned short* vbuf  = (unsigned short*)alloc((size_t)BHEADS * NSEQ * DH * 2);
  float2* cst           = (float2*)alloc((size_t)NSEQ * DH * sizeof(float2));
  unsigned short* aob   = xb;   // xb dead after gemm1; reuse for attn output

  (void)hipFuncSetAttribute((const void*)gemm256<1>,
      hipFuncAttributeMaxDynamicSharedMemorySize, 131072);
  (void)hipFuncSetAttribute((const void*)gemm256<0>,
      hipFuncAttributeMaxDynamicSharedMemorySize, 131072);

  cvt_bf16<<<2048, 256, 0, stream>>>(x, xb, MROWS * DIMC / 8);
  cvt_bf16<<<2048, 256, 0, stream>>>(Wqkv, wqkvb, NQKV * DIMC / 8);
  cvt_bf16<<<1024, 256, 0, stream>>>(Wout, woutb, DIMC * DIMC / 8);
  build_cs<<<(NSEQ * DH + 255) / 256, 256, 0, stream>>>(freqs, cst, NSEQ * DH);

  gemm256<1><<<dim3(NQKV / 256, MROWS / 256), 512, 131072, stream>>>(
      xb, wqkvb, DIMC, NQKV, nullptr, qbuf, kbuf, vbuf, cst);

  attn_fa<<<dim3(NSEQ / 128, BHEADS), 256, 0, stream>>>(qbuf, kbuf, vbuf, aob);

  gemm256<0><<<dim3(DIMC / 256, MROWS / 256), 512, 131072, stream>>>(
      aob, woutb, DIMC, DIMC, out, nullptr, nullptr, nullptr, nullptr);
}

// Round 5
// 497.225 us; speedup vs baseline: 1.0167x; 1.0167x over previous
//
#include <hip/hip_runtime.h>

#define DIMC 2048
#define NSEQ 2048
#define NBATCH 2
#define NH 32
#define DH 64
#define BHEADS (NBATCH*NH)      // 64
#define MROWS (NBATCH*NSEQ)     // 4096
#define NQKV (3*DIMC)           // 6144

typedef __attribute__((ext_vector_type(8))) short short8;
typedef __attribute__((ext_vector_type(4))) float f32x4;
typedef __attribute__((ext_vector_type(4))) unsigned int uint4v;
typedef __attribute__((ext_vector_type(2))) unsigned int u32x2;

static __device__ __forceinline__ unsigned short f2bf(float f) {
  union { float f; unsigned int u; } v; v.f = f;
  unsigned int r = (v.u + 0x7FFFu + ((v.u >> 16) & 1u)) >> 16;
  return (unsigned short)r;
}

static __device__ __forceinline__ unsigned int cvt_pk_bf16(float lo, float hi) {
  unsigned int r;
  asm("v_cvt_pk_bf16_f32 %0, %1, %2" : "=v"(r) : "v"(lo), "v"(hi));
  return r;
}

#define BAR()    __builtin_amdgcn_s_barrier()
#define LGKM0()  asm volatile("s_waitcnt lgkmcnt(0)" ::: "memory")
#define LGKM8()  asm volatile("s_waitcnt lgkmcnt(8)" ::: "memory")
#define VM(n)    asm volatile("s_waitcnt vmcnt(" #n ")" ::: "memory")

// ---------------- fp32 -> bf16 convert (vectorized, grid-stride) ------------
__global__ __launch_bounds__(256) void cvt_bf16(const float* __restrict__ in,
                                                unsigned short* __restrict__ out,
                                                int n8) {
  int i = blockIdx.x * blockDim.x + threadIdx.x;
  int stride = gridDim.x * blockDim.x;
  for (; i < n8; i += stride) {
    const float4* p = (const float4*)in + (size_t)i * 2;
    float4 a = p[0], b = p[1];
    union { unsigned short u[8]; uint4v v; } o;
    o.u[0] = f2bf(a.x); o.u[1] = f2bf(a.y); o.u[2] = f2bf(a.z); o.u[3] = f2bf(a.w);
    o.u[4] = f2bf(b.x); o.u[5] = f2bf(b.y); o.u[6] = f2bf(b.z); o.u[7] = f2bf(b.w);
    *((uint4v*)out + i) = o.v;
  }
}

// ---------------- cos/sin table --------------------------------------------
__global__ __launch_bounds__(256) void build_cs(const float* __restrict__ freqs,
                                                float2* __restrict__ cs, int n) {
  int i = blockIdx.x * blockDim.x + threadIdx.x;
  if (i < n) { float f = freqs[i]; cs[i] = make_float2(cosf(f), sinf(f)); }
}

// ---------------- 256x256 8-phase GEMM: C = A[M,K] * B[N,K]^T ---------------
// 512 thr (8 waves 2Mx4N), BK=64, 128KB dbuf LDS, st_16x32 swizzle,
// counted vmcnt(4), setprio around MFMA, XCD-swizzled blockIdx.
// launch_bounds(512,1): 8-wave block => hard 256-VGPR cap; (512,2) spilled
// (R4: VGPR_Count=128, +36MB scratch writes, MfmaUtil 15.6%).
#define QSCALE 0.18033688011112042f   // (1/8) * log2(e)

template<int EPI>
__global__ __launch_bounds__(512, 1) void gemm256(
    const unsigned short* __restrict__ A,
    const unsigned short* __restrict__ Bm,
    int Kdim, int Ncols,
    float* __restrict__ Cout,
    unsigned short* __restrict__ qo, unsigned short* __restrict__ ko,
    unsigned short* __restrict__ vo, const float2* __restrict__ cs)
{
  extern __shared__ char Lds[];   // 131072 bytes
  const int t = threadIdx.x;
  const int w = t >> 6, lane = t & 63, lr = lane & 15, g = lane >> 4;
  const int wm = w >> 2, wn = w & 3;
  const int gx = (g * 16) ^ ((lr & 4) << 3);       // swizzled in-row byte offset

  // XCD-aware bijective swizzle (grid counts are multiples of 8)
  const int nx = gridDim.x;
  int orig = blockIdx.y * nx + blockIdx.x;
  int cpx = (nx * gridDim.y) >> 3;
  int id = (orig & 7) * cpx + (orig >> 3);
  const int m0 = (id / nx) * 256;
  const int n0 = (id % nx) * 256;

  // staging lane offsets (32-bit, element units); half/c/T terms are uniform
  const int lp = lane ^ ((lane & 32) >> 4);        // flip bit1 when bit5 set
  const int offA = (m0 + w * 16 + (lp >> 3)) * Kdim + (lp & 7) * 8;
  const int offB = (n0 + w * 16 + (lp >> 3)) * Kdim + (lp & 7) * 8;

  auto STAGE = [&](int op, int half, int buf, int T) {
    const unsigned short* base = (op ? Bm : A) + (op ? offB : offA)
                                 + (size_t)(half * 128) * Kdim + T * 64;
    char* d = Lds + buf * 65536 + op * 32768 + half * 16384 + w * 2048;
    __builtin_amdgcn_global_load_lds(
        (const __attribute__((address_space(1))) void*)base,
        (__attribute__((address_space(3))) void*)d, 16, 0, 0);
    __builtin_amdgcn_global_load_lds(
        (const __attribute__((address_space(1))) void*)(base + 8 * Kdim),
        (__attribute__((address_space(3))) void*)(d + 1024), 16, 0, 0);
  };

  short8 A0r[2][4], A1r[2][4], B0r[2][2], B1r[2][2];  // [ks][frag]

  auto LDA = [&](short8 (&dst)[2][4], int bufb, int mlo) {
    const char* bp = Lds + bufb + wm * 16384 + (mlo * 16 + lr) * 128 + gx;
    #pragma unroll
    for (int ks = 0; ks < 2; ks++)
      #pragma unroll
      for (int mm = 0; mm < 4; mm++)
        dst[ks][mm] = *(const short8*)(bp + mm * 2048 + ks * 64);
  };
  auto LDB = [&](short8 (&dst)[2][2], int bufb, int nlo) {
    const char* bp = Lds + bufb + 32768 + (wn >> 1) * 16384 + (wn & 1) * 8192
                     + (nlo * 16 + lr) * 128 + gx;
    #pragma unroll
    for (int ks = 0; ks < 2; ks++)
      #pragma unroll
      for (int nn = 0; nn < 2; nn++)
        dst[ks][nn] = *(const short8*)(bp + nn * 2048 + ks * 64);
  };

  f32x4 acc[8][4];
  f32x4 zero = {0.0f, 0.0f, 0.0f, 0.0f};
  #pragma unroll
  for (int i = 0; i < 8; i++)
    #pragma unroll
    for (int j = 0; j < 4; j++) acc[i][j] = zero;

  auto MM = [&](short8 (&Af)[2][4], short8 (&Bf)[2][2], int mq, int nq) {
    __builtin_amdgcn_s_setprio(1);
    #pragma unroll
    for (int mm = 0; mm < 4; mm++)
      #pragma unroll
      for (int nn = 0; nn < 2; nn++)
        #pragma unroll
        for (int ks = 0; ks < 2; ks++)
          acc[mq * 4 + mm][nq * 2 + nn] = __builtin_amdgcn_mfma_f32_16x16x32_bf16(
              Af[ks][mm], Bf[ks][nn], acc[mq * 4 + mm][nq * 2 + nn], 0, 0, 0);
    __builtin_amdgcn_s_setprio(0);
  };

  // ---- prologue: tile0 complete + tile1 {Ah0,Bh0,Ah1}; wait tile 0 ----
  STAGE(0,0,0, 0); STAGE(1,0,0, 0); STAGE(0,1,0, 0); STAGE(1,1,0, 0);
  STAGE(0,0,1, 1); STAGE(1,0,1, 1); STAGE(0,1,1, 1);
  VM(6);            // 14 issued; wait -> tile 0's 8 loads landed
  BAR();
  LDA(A0r, 0, 0); LDB(B0r, 0, 0);

  const int NIT = Kdim >> 7;   // 2 K-tiles (BK=64) per iteration
  for (int i = 0; i < NIT; i++) {
    const bool more = (i < NIT - 1);
    const int Tc  = 2 * i + 1;   // current odd tile (buf1): finish its Bh1
    const int Tn0 = 2 * i + 2;   // next even tile -> buf0
    const int Tn1 = 2 * i + 3;   // next odd tile  -> buf1
    // ph0: q(0,0) even tile; stage Bh1@buf1 for tile Tc (buf1-B last read ph5-prev)
    LDA(A1r, 0, 4);
    STAGE(1,1,1, Tc);
    BAR(); LGKM0(); MM(A0r, B0r, 0, 0); BAR();
    // ph1: stage Ah0@buf0 (buf0-A last read ph0)
    LDB(B1r, 0, 2);
    if (more) STAGE(0,0,0, Tn0);
    BAR(); LGKM0(); MM(A1r, B0r, 1, 0); BAR();
    // ph2: stage Bh0@buf0 (buf0-B last read ph1); guard buf1 tile Tc before ph3
    if (more) STAGE(1,0,0, Tn0);
    BAR(); LGKM0(); MM(A1r, B1r, 1, 1);
    if (more) { VM(4); } else { VM(0); }
    BAR();
    // ph3: read buf1 (tile Tc); stage Ah1@buf0
    LDA(A1r, 65536, 0); LDB(B0r, 65536, 0);
    if (more) STAGE(0,1,0, Tn0);
    LGKM8();
    BAR(); LGKM0(); MM(A0r, B1r, 0, 1); BAR();
    // ph4: stage Bh1@buf0 (tile Tn0 complete)
    LDA(A0r, 65536, 4);
    if (more) STAGE(1,1,0, Tn0);
    BAR(); LGKM0(); MM(A1r, B0r, 0, 0); BAR();
    // ph5: stage Ah0@buf1 (buf1-A last read ph4)
    LDB(B1r, 65536, 2);
    if (more) STAGE(0,0,1, Tn1);
    BAR(); LGKM0(); MM(A0r, B0r, 1, 0); BAR();
    // ph6: stage Bh0@buf1 (buf1-B last read ph5); guard buf0 tile Tn0 before ph7
    if (more) STAGE(1,0,1, Tn1);
    BAR(); LGKM0(); MM(A0r, B1r, 1, 1);
    if (more) VM(4);
    BAR();
    // ph7: prefetch-read buf0 (tile Tn0); stage Ah1@buf1
    if (more) {
      LDA(A0r, 0, 0); LDB(B0r, 0, 0);
      STAGE(0,1,1, Tn1);
      LGKM8();
    }
    BAR(); LGKM0(); MM(A1r, B1r, 0, 1); BAR();
  }

  // ---- epilogue ----
  if (EPI == 0) {
    #pragma unroll
    for (int m = 0; m < 8; m++) {
      #pragma unroll
      for (int r = 0; r < 4; r++) {
        int row = m0 + wm * 128 + m * 16 + g * 4 + r;
        #pragma unroll
        for (int n = 0; n < 4; n++)
          Cout[(size_t)row * Ncols + (n0 + wn * 64 + n * 16 + lr)] = acc[m][n][r];
      }
    }
  } else {
    const int which = n0 >> 11;
    const int head = ((n0 & 2047) + wn * 64) >> 6;
    #pragma unroll
    for (int m = 0; m < 8; m++) {
      #pragma unroll
      for (int r = 0; r < 4; r++) {
        int row = m0 + wm * 128 + m * 16 + g * 4 + r;
        int b = row >> 11, ntok = row & 2047;
        size_t obase = ((size_t)(b * NH + head) * NSEQ + ntok) * DH;
        #pragma unroll
        for (int n = 0; n < 4; n++) {
          int d = n * 16 + lr;
          float val = acc[m][n][r];
          if (which == 2) {
            vo[obase + d] = f2bf(val);
          } else {
            float other = acc[m][n ^ 2][r];
            float2 c2 = cs[ntok * DH + d];
            float rot = (d < 32) ? (val * c2.x - other * c2.y)
                                 : (val * c2.x + other * c2.y);
            if (which == 0) qo[obase + d] = f2bf(rot * QSCALE);
            else            ko[obase + d] = f2bf(rot);
          }
        }
      }
    }
  }
}

// ---------------- flash attention: 4 waves x 32 q, KVBLK=64 -----------------
__global__ __launch_bounds__(256, 4) void attn_fa(
    const unsigned short* __restrict__ qb,
    const unsigned short* __restrict__ kb,
    const unsigned short* __restrict__ vb,
    unsigned short* __restrict__ aob)
{
  __shared__ __align__(16) unsigned short Kl[64 * 64];      // linear, XOR-swizzled content
  __shared__ __align__(16) unsigned short Vt[64 * 72];      // [d][k + pad8]
  __shared__ __align__(16) unsigned short Pl[4][32 * 72];   // per-wave [q][k + pad8]

  const int t = threadIdx.x;
  const int w = t >> 6, lane = t & 63, lr = lane & 15, g = lane >> 4;
  const int bh = blockIdx.y;
  const int q0 = blockIdx.x * 128 + w * 32;
  const size_t hbase = (size_t)bh * NSEQ * DH;

  short8 qf[2][2];
  #pragma unroll
  for (int qt = 0; qt < 2; qt++)
    #pragma unroll
    for (int hf = 0; hf < 2; hf++)
      qf[qt][hf] = *(const short8*)(qb + hbase + (size_t)(q0 + qt * 16 + lr) * DH + hf * 32 + g * 8);

  f32x4 zero = {0.0f, 0.0f, 0.0f, 0.0f};
  f32x4 oacc[2][4];
  #pragma unroll
  for (int qt = 0; qt < 2; qt++)
    #pragma unroll
    for (int dv = 0; dv < 4; dv++) oacc[qt][dv] = zero;
  float mrun[2] = {-1e30f, -1e30f};
  float lrun[2] = {0.0f, 0.0f};

  int kro[2], kdo_[2];
  #pragma unroll
  for (int c = 0; c < 2; c++) {
    int b = w * 2048 + c * 1024 + lane * 16;
    int row = b >> 7;
    int off = b ^ ((row & 7) << 4);
    kro[c] = row;
    kdo_[c] = (off >> 1) & 63;
  }
  const int vr0 = (t & 31) * 2;
  const int vhv = (t >> 5) * 8;

  unsigned short* prow0 = &Pl[w][lr * 72];
  unsigned short* prow1 = &Pl[w][(16 + lr) * 72];

  for (int kv0 = 0; kv0 < NSEQ; kv0 += 64) {
    __syncthreads();
    #pragma unroll
    for (int c = 0; c < 2; c++) {
      const unsigned short* src = kb + hbase + (size_t)(kv0 + kro[c]) * DH + kdo_[c];
      __builtin_amdgcn_global_load_lds(
          (const __attribute__((address_space(1))) void*)src,
          (__attribute__((address_space(3))) void*)(Kl + w * 1024 + c * 512), 16, 0, 0);
    }
    {
      const unsigned short* s0 = vb + hbase + (size_t)(kv0 + vr0) * DH + vhv;
      short8 v0 = *(const short8*)(s0);
      short8 v1 = *(const short8*)(s0 + DH);
      #pragma unroll
      for (int j = 0; j < 8; j++) {
        unsigned int p = ((unsigned short)v0[j]) | (((unsigned int)(unsigned short)v1[j]) << 16);
        *(unsigned int*)&Vt[(vhv + j) * 72 + vr0] = p;
      }
    }
    __syncthreads();

    f32x4 s[2][4];
    #pragma unroll
    for (int kt = 0; kt < 4; kt++) {
      int row = kt * 16 + lr;
      int sw = (row & 7) << 4;
      int byteA = (row * 128 + g * 16) ^ sw;
      int byteB = (row * 128 + 64 + g * 16) ^ sw;
      short8 kA = *(const short8*)((const char*)Kl + byteA);
      short8 kB = *(const short8*)((const char*)Kl + byteB);
      #pragma unroll
      for (int qt = 0; qt < 2; qt++) {
        f32x4 a0 = __builtin_amdgcn_mfma_f32_16x16x32_bf16(kA, qf[qt][0], zero, 0, 0, 0);
        s[qt][kt] = __builtin_amdgcn_mfma_f32_16x16x32_bf16(kB, qf[qt][1], a0, 0, 0, 0);
      }
    }

    float nm[2];
    #pragma unroll
    for (int qt = 0; qt < 2; qt++) {
      f32x4 m01 = s[qt][0];
      #pragma unroll
      for (int kt = 1; kt < 4; kt++) {
        f32x4 sv = s[qt][kt];
        m01[0] = fmaxf(m01[0], sv[0]); m01[1] = fmaxf(m01[1], sv[1]);
        m01[2] = fmaxf(m01[2], sv[2]); m01[3] = fmaxf(m01[3], sv[3]);
      }
      float v = fmaxf(fmaxf(m01[0], m01[1]), fmaxf(m01[2], m01[3]));
      v = fmaxf(v, __shfl_xor(v, 16));
      v = fmaxf(v, __shfl_xor(v, 32));
      nm[qt] = v;
    }

    if (!__all(fmaxf(nm[0] - mrun[0], nm[1] - mrun[1]) <= 8.0f)) {
      const int sb = (lane & 48) + ((lane & 48) >> 2);
      #pragma unroll
      for (int qt = 0; qt < 2; qt++) {
        float m2 = fmaxf(mrun[qt], nm[qt]);
        float cc = exp2f(mrun[qt] - m2);
        mrun[qt] = m2;
        lrun[qt] *= cc;
        float c0r = __shfl(cc, sb + 0);
        float c1r = __shfl(cc, sb + 1);
        float c2r = __shfl(cc, sb + 2);
        float c3r = __shfl(cc, sb + 3);
        #pragma unroll
        for (int dv = 0; dv < 4; dv++) {
          f32x4 a = oacc[qt][dv];
          a[0] *= c0r; a[1] *= c1r; a[2] *= c2r; a[3] *= c3r;
          oacc[qt][dv] = a;
        }
      }
    }

    #pragma unroll
    for (int qt = 0; qt < 2; qt++) {
      float mq = mrun[qt];
      float ls = 0.0f;
      unsigned short* prow = qt ? prow1 : prow0;
      #pragma unroll
      for (int kt = 0; kt < 4; kt++) {
        f32x4 sv = s[qt][kt];
        float p0 = exp2f(sv[0] - mq), p1 = exp2f(sv[1] - mq);
        float p2 = exp2f(sv[2] - mq), p3 = exp2f(sv[3] - mq);
        ls += (p0 + p1) + (p2 + p3);
        u32x2 uu;
        uu.x = cvt_pk_bf16(p0, p1);
        uu.y = cvt_pk_bf16(p2, p3);
        *(u32x2*)(prow + kt * 16 + g * 4) = uu;
      }
      ls += __shfl_xor(ls, 16);
      ls += __shfl_xor(ls, 32);
      lrun[qt] += ls;
    }

    #pragma unroll
    for (int c0 = 0; c0 < 2; c0++) {
      short8 pa0 = *(const short8*)(prow0 + c0 * 32 + g * 8);
      short8 pa1 = *(const short8*)(prow1 + c0 * 32 + g * 8);
      #pragma unroll
      for (int dv = 0; dv < 4; dv++) {
        short8 vf = *(const short8*)&Vt[(dv * 16 + lr) * 72 + c0 * 32 + g * 8];
        oacc[0][dv] = __builtin_amdgcn_mfma_f32_16x16x32_bf16(pa0, vf, oacc[0][dv], 0, 0, 0);
        oacc[1][dv] = __builtin_amdgcn_mfma_f32_16x16x32_bf16(pa1, vf, oacc[1][dv], 0, 0, 0);
      }
    }
  }

  const int b = bh >> 5, h = bh & 31;
  const int sb = (lane & 48) + ((lane & 48) >> 2);
  #pragma unroll
  for (int qt = 0; qt < 2; qt++) {
    float inv = 1.0f / lrun[qt];
    float ir[4];
    ir[0] = __shfl(inv, sb + 0);
    ir[1] = __shfl(inv, sb + 1);
    ir[2] = __shfl(inv, sb + 2);
    ir[3] = __shfl(inv, sb + 3);
    #pragma unroll
    for (int r = 0; r < 4; r++) {
      int ntok = q0 + qt * 16 + g * 4 + r;
      size_t ob = ((size_t)(b * NSEQ + ntok)) * DIMC + h * DH;
      #pragma unroll
      for (int dv = 0; dv < 4; dv++)
        aob[ob + dv * 16 + lr] = f2bf(oacc[qt][dv][r] * ir[r]);
    }
  }
}

// ---------------------------------------------------------------------------
extern "C" void kernel_launch(void* const* d_in, const int* in_sizes, int n_in,
                              void* d_out, int out_size, void* d_ws, size_t ws_size,
                              hipStream_t stream) {
  const float* x     = (const float*)d_in[0];
  const float* freqs = (const float*)d_in[1];
  const float* Wqkv  = (const float*)d_in[2];
  const float* Wout  = (const float*)d_in[3];
  float* out = (float*)d_out;

  char* ws = (char*)d_ws;
  size_t off = 0;
  auto alloc = [&](size_t bytes) {
    void* p = ws + off;
    off += (bytes + 255) & ~(size_t)255;
    return p;
  };
  unsigned short* xb    = (unsigned short*)alloc((size_t)MROWS * DIMC * 2);
  unsigned short* wqkvb = (unsigned short*)alloc((size_t)NQKV * DIMC * 2);
  unsigned short* woutb = (unsigned short*)alloc((size_t)DIMC * DIMC * 2);
  unsigned short* qbuf  = (unsigned short*)alloc((size_t)BHEADS * NSEQ * DH * 2);
  unsigned short* kbuf  = (unsigned short*)alloc((size_t)BHEADS * NSEQ * DH * 2);
  unsigned short* vbuf  = (unsigned short*)alloc((size_t)BHEADS * NSEQ * DH * 2);
  float2* cst           = (float2*)alloc((size_t)NSEQ * DH * sizeof(float2));
  unsigned short* aob   = xb;   // xb dead after gemm1; reuse for attn output

  (void)hipFuncSetAttribute((const void*)gemm256<1>,
      hipFuncAttributeMaxDynamicSharedMemorySize, 131072);
  (void)hipFuncSetAttribute((const void*)gemm256<0>,
      hipFuncAttributeMaxDynamicSharedMemorySize, 131072);

  cvt_bf16<<<2048, 256, 0, stream>>>(x, xb, MROWS * DIMC / 8);
  cvt_bf16<<<2048, 256, 0, stream>>>(Wqkv, wqkvb, NQKV * DIMC / 8);
  cvt_bf16<<<1024, 256, 0, stream>>>(Wout, woutb, DIMC * DIMC / 8);
  build_cs<<<(NSEQ * DH + 255) / 256, 256, 0, stream>>>(freqs, cst, NSEQ * DH);

  gemm256<1><<<dim3(NQKV / 256, MROWS / 256), 512, 131072, stream>>>(
      xb, wqkvb, DIMC, NQKV, nullptr, qbuf, kbuf, vbuf, cst);

  attn_fa<<<dim3(NSEQ / 128, BHEADS), 256, 0, stream>>>(qbuf, kbuf, vbuf, aob);

  gemm256<0><<<dim3(DIMC / 256, MROWS / 256), 512, 131072, stream>>>(
      aob, woutb, DIMC, DIMC, out, nullptr, nullptr, nullptr, nullptr);
}

// Round 7
// 373.991 us; speedup vs baseline: 1.3518x; 1.3295x over previous
//
#include <hip/hip_runtime.h>

#define DIMC 2048
#define NSEQ 2048
#define NBATCH 2
#define NH 32
#define DH 64
#define BHEADS (NBATCH*NH)      // 64
#define MROWS (NBATCH*NSEQ)     // 4096
#define NQKV (3*DIMC)           // 6144

typedef __attribute__((ext_vector_type(8))) short short8;
typedef __attribute__((ext_vector_type(4))) float f32x4;
typedef __attribute__((ext_vector_type(4))) unsigned int uint4v;
typedef __attribute__((ext_vector_type(2))) unsigned int u32x2;

static __device__ __forceinline__ unsigned short f2bf(float f) {
  union { float f; unsigned int u; } v; v.f = f;
  unsigned int r = (v.u + 0x7FFFu + ((v.u >> 16) & 1u)) >> 16;
  return (unsigned short)r;
}

static __device__ __forceinline__ unsigned int cvt_pk_bf16(float lo, float hi) {
  unsigned int r;
  asm("v_cvt_pk_bf16_f32 %0, %1, %2" : "=v"(r) : "v"(lo), "v"(hi));
  return r;
}

#define BAR()    __builtin_amdgcn_s_barrier()
#define FENCE()  asm volatile("" ::: "memory")
#define LGKM0()  asm volatile("s_waitcnt lgkmcnt(0)" ::: "memory")
#define VM(n)    asm volatile("s_waitcnt vmcnt(" #n ")" ::: "memory")

// ---------------- fp32 -> bf16 convert (vectorized, grid-stride) ------------
__global__ __launch_bounds__(256) void cvt_bf16(const float* __restrict__ in,
                                                unsigned short* __restrict__ out,
                                                int n8) {
  int i = blockIdx.x * blockDim.x + threadIdx.x;
  int stride = gridDim.x * blockDim.x;
  for (; i < n8; i += stride) {
    const float4* p = (const float4*)in + (size_t)i * 2;
    float4 a = p[0], b = p[1];
    union { unsigned short u[8]; uint4v v; } o;
    o.u[0] = f2bf(a.x); o.u[1] = f2bf(a.y); o.u[2] = f2bf(a.z); o.u[3] = f2bf(a.w);
    o.u[4] = f2bf(b.x); o.u[5] = f2bf(b.y); o.u[6] = f2bf(b.z); o.u[7] = f2bf(b.w);
    *((uint4v*)out + i) = o.v;
  }
}

// ---------------- cos/sin table --------------------------------------------
__global__ __launch_bounds__(256) void build_cs(const float* __restrict__ freqs,
                                                float2* __restrict__ cs, int n) {
  int i = blockIdx.x * blockDim.x + threadIdx.x;
  if (i < n) { float f = freqs[i]; cs[i] = make_float2(cosf(f), sinf(f)); }
}

// ---------------- 256x256 8-phase GEMM: C = A[M,K] * B[N,K]^T ---------------
// 512 thr (8 waves 2Mx4N), BK=64, 128KB dbuf LDS, st-swizzle, JIT per-phase
// fragment loads. Sync discipline (R6 race fix): tile-boundary VM(0) sits at
// the END of the previous phase, before its closing barrier -> barrier makes
// the per-wave vmcnt drain collective across all 8 staging waves. ds_reads of
// a freshly staged tile only occur in the window AFTER that barrier.
#define QSCALE 0.18033688011112042f   // (1/8) * log2(e)

template<int EPI>
__global__ __launch_bounds__(512, 1) void gemm256(
    const unsigned short* __restrict__ A,
    const unsigned short* __restrict__ Bm,
    int Kdim, int Ncols,
    float* __restrict__ Cout,
    unsigned short* __restrict__ qo, unsigned short* __restrict__ ko,
    unsigned short* __restrict__ vo, const float2* __restrict__ cs)
{
  extern __shared__ char Lds[];   // 131072 bytes
  const int t = threadIdx.x;
  const int w = t >> 6, lane = t & 63, lr = lane & 15, g = lane >> 4;
  const int wm = w >> 2, wn = w & 3;
  const int gx = (g * 16) ^ ((lr & 4) << 3);       // swizzled in-row byte offset

  // XCD-aware bijective swizzle (grid counts are multiples of 8)
  const int nx = gridDim.x;
  int orig = blockIdx.y * nx + blockIdx.x;
  int cpx = (nx * gridDim.y) >> 3;
  int id = (orig & 7) * cpx + (orig >> 3);
  const int m0 = (id / nx) * 256;
  const int n0 = (id % nx) * 256;

  // staging: wave w covers rows (w>>2)*128 + (w&3)*32 + j*8 (j=0..3)
  const int lp = lane ^ ((lane & 32) >> 4);        // write-side inverse swizzle
  const int laneoff = (lp >> 3) * Kdim + (lp & 7) * 8;
  const int rowA = m0 + (w >> 2) * 128 + (w & 3) * 32;
  const int rowB = n0 + (w >> 2) * 128 + (w & 3) * 32;
  const unsigned short* Abase = A + (size_t)rowA * Kdim + laneoff;
  const unsigned short* Bbase = Bm + (size_t)rowB * Kdim + laneoff;
  char* dstb = Lds + (w >> 2) * 16384 + (w & 3) * 4096;

  auto STAGE_A = [&](int buf, int T) {
    const unsigned short* s = Abase + T * 64;
    char* d = dstb + buf * 65536;
    #pragma unroll
    for (int j = 0; j < 4; j++)
      __builtin_amdgcn_global_load_lds(
          (const __attribute__((address_space(1))) void*)(s + j * 8 * Kdim),
          (__attribute__((address_space(3))) void*)(d + j * 1024), 16, 0, 0);
  };
  auto STAGE_B = [&](int buf, int T) {
    const unsigned short* s = Bbase + T * 64;
    char* d = dstb + buf * 65536 + 32768;
    #pragma unroll
    for (int j = 0; j < 4; j++)
      __builtin_amdgcn_global_load_lds(
          (const __attribute__((address_space(1))) void*)(s + j * 8 * Kdim),
          (__attribute__((address_space(3))) void*)(d + j * 1024), 16, 0, 0);
  };

  short8 X[2][4], Y[2][4], P[2][2], Q[2][2];  // JIT fragment sets

  auto LDA = [&](short8 (&dst)[2][4], int bufb, int mlo) {
    const char* bp = Lds + bufb + wm * 16384 + (mlo * 16 + lr) * 128 + gx;
    #pragma unroll
    for (int ks = 0; ks < 2; ks++)
      #pragma unroll
      for (int mm = 0; mm < 4; mm++)
        dst[ks][mm] = *(const short8*)(bp + mm * 2048 + ks * 64);
  };
  auto LDB = [&](short8 (&dst)[2][2], int bufb, int nlo) {
    const char* bp = Lds + bufb + 32768 + (wn >> 1) * 16384 + (wn & 1) * 8192
                     + (nlo * 16 + lr) * 128 + gx;
    #pragma unroll
    for (int ks = 0; ks < 2; ks++)
      #pragma unroll
      for (int nn = 0; nn < 2; nn++)
        dst[ks][nn] = *(const short8*)(bp + nn * 2048 + ks * 64);
  };

  f32x4 acc[8][4];
  f32x4 zero = {0.0f, 0.0f, 0.0f, 0.0f};
  #pragma unroll
  for (int i = 0; i < 8; i++)
    #pragma unroll
    for (int j = 0; j < 4; j++) acc[i][j] = zero;

  auto MM = [&](short8 (&Af)[2][4], short8 (&Bf)[2][2], int mq, int nq) {
    __builtin_amdgcn_s_setprio(1);
    #pragma unroll
    for (int mm = 0; mm < 4; mm++)
      #pragma unroll
      for (int nn = 0; nn < 2; nn++)
        #pragma unroll
        for (int ks = 0; ks < 2; ks++)
          acc[mq * 4 + mm][nq * 2 + nn] = __builtin_amdgcn_mfma_f32_16x16x32_bf16(
              Af[ks][mm], Bf[ks][nn], acc[mq * 4 + mm][nq * 2 + nn], 0, 0, 0);
    __builtin_amdgcn_s_setprio(0);
  };

  // ---- prologue: stage tile 0 -> buf0; collective drain ----
  STAGE_A(0, 0); STAGE_B(0, 0);
  VM(0);
  BAR(); FENCE();

  const int NI2 = Kdim >> 7;   // 2 K-tiles (BK=64) per iteration
  for (int i = 0; i < NI2; i++) {
    const bool more = (i < NI2 - 1);
    const int te = 2 * i, to = 2 * i + 1;
    // ---- even tile (buf0) ----
    // ph0: read q(0,0) frags of buf0; stage A(to) -> buf1
    LDA(X, 0, 0); LDB(P, 0, 0);
    STAGE_A(1, to);
    BAR(); LGKM0(); MM(X, P, 0, 0); BAR(); FENCE();
    // ph1: stage B(to) -> buf1
    LDA(Y, 0, 4);
    STAGE_B(1, to);
    BAR(); LGKM0(); MM(Y, P, 1, 0); BAR(); FENCE();
    // ph2
    LDB(Q, 0, 2);
    BAR(); LGKM0(); MM(Y, Q, 1, 1); BAR(); FENCE();
    // ph3: re-read A-h0; drain tile to (8 loads, issued ph0/ph1) pre-barrier
    LDA(X, 0, 0);
    BAR(); LGKM0(); MM(X, Q, 0, 1);
    VM(0);
    BAR(); FENCE();
    // ---- odd tile (buf1) ----
    // ph4: read buf1; stage A(te+2) -> buf0
    LDA(X, 65536, 0); LDB(P, 65536, 0);
    if (more) STAGE_A(0, te + 2);
    BAR(); LGKM0(); MM(X, P, 0, 0); BAR(); FENCE();
    // ph5: stage B(te+2) -> buf0
    LDA(Y, 65536, 4);
    if (more) STAGE_B(0, te + 2);
    BAR(); LGKM0(); MM(Y, P, 1, 0); BAR(); FENCE();
    // ph6
    LDB(Q, 65536, 2);
    BAR(); LGKM0(); MM(Y, Q, 1, 1); BAR(); FENCE();
    // ph7: re-read A-h0; drain tile te+2 pre-barrier (no-op on last iter)
    LDA(X, 65536, 0);
    BAR(); LGKM0(); MM(X, Q, 0, 1);
    VM(0);
    BAR(); FENCE();
  }

  // ---- epilogue ----
  if (EPI == 0) {
    #pragma unroll
    for (int m = 0; m < 8; m++) {
      #pragma unroll
      for (int r = 0; r < 4; r++) {
        int row = m0 + wm * 128 + m * 16 + g * 4 + r;
        #pragma unroll
        for (int n = 0; n < 4; n++)
          Cout[(size_t)row * Ncols + (n0 + wn * 64 + n * 16 + lr)] = acc[m][n][r];
      }
    }
  } else {
    const int which = n0 >> 11;
    const int head = ((n0 & 2047) + wn * 64) >> 6;
    #pragma unroll
    for (int m = 0; m < 8; m++) {
      #pragma unroll
      for (int r = 0; r < 4; r++) {
        int row = m0 + wm * 128 + m * 16 + g * 4 + r;
        int b = row >> 11, ntok = row & 2047;
        size_t obase = ((size_t)(b * NH + head) * NSEQ + ntok) * DH;
        #pragma unroll
        for (int n = 0; n < 4; n++) {
          int d = n * 16 + lr;
          float val = acc[m][n][r];
          if (which == 2) {
            vo[obase + d] = f2bf(val);
          } else {
            float other = acc[m][n ^ 2][r];
            float2 c2 = cs[ntok * DH + d];
            float rot = (d < 32) ? (val * c2.x - other * c2.y)
                                 : (val * c2.x + other * c2.y);
            if (which == 0) qo[obase + d] = f2bf(rot * QSCALE);
            else            ko[obase + d] = f2bf(rot);
          }
        }
      }
    }
  }
}

// ---------------- flash attention: 4 waves x 32 q, KVBLK=64 -----------------
__global__ __launch_bounds__(256, 4) void attn_fa(
    const unsigned short* __restrict__ qb,
    const unsigned short* __restrict__ kb,
    const unsigned short* __restrict__ vb,
    unsigned short* __restrict__ aob)
{
  __shared__ __align__(16) unsigned short Kl[64 * 64];      // linear, XOR-swizzled content
  __shared__ __align__(16) unsigned short Vt[64 * 72];      // [d][k + pad8]
  __shared__ __align__(16) unsigned short Pl[4][32 * 72];   // per-wave [q][k + pad8]

  const int t = threadIdx.x;
  const int w = t >> 6, lane = t & 63, lr = lane & 15, g = lane >> 4;
  const int bh = blockIdx.y;
  const int q0 = blockIdx.x * 128 + w * 32;
  const size_t hbase = (size_t)bh * NSEQ * DH;

  short8 qf[2][2];
  #pragma unroll
  for (int qt = 0; qt < 2; qt++)
    #pragma unroll
    for (int hf = 0; hf < 2; hf++)
      qf[qt][hf] = *(const short8*)(qb + hbase + (size_t)(q0 + qt * 16 + lr) * DH + hf * 32 + g * 8);

  f32x4 zero = {0.0f, 0.0f, 0.0f, 0.0f};
  f32x4 oacc[2][4];
  #pragma unroll
  for (int qt = 0; qt < 2; qt++)
    #pragma unroll
    for (int dv = 0; dv < 4; dv++) oacc[qt][dv] = zero;
  float mrun[2] = {-1e30f, -1e30f};
  float lrun[2] = {0.0f, 0.0f};

  int kro[2], kdo_[2];
  #pragma unroll
  for (int c = 0; c < 2; c++) {
    int b = w * 2048 + c * 1024 + lane * 16;
    int row = b >> 7;
    int off = b ^ ((row & 7) << 4);
    kro[c] = row;
    kdo_[c] = (off >> 1) & 63;
  }
  const int vr0 = (t & 31) * 2;
  const int vhv = (t >> 5) * 8;

  unsigned short* prow0 = &Pl[w][lr * 72];
  unsigned short* prow1 = &Pl[w][(16 + lr) * 72];

  for (int kv0 = 0; kv0 < NSEQ; kv0 += 64) {
    __syncthreads();
    #pragma unroll
    for (int c = 0; c < 2; c++) {
      const unsigned short* src = kb + hbase + (size_t)(kv0 + kro[c]) * DH + kdo_[c];
      __builtin_amdgcn_global_load_lds(
          (const __attribute__((address_space(1))) void*)src,
          (__attribute__((address_space(3))) void*)(Kl + w * 1024 + c * 512), 16, 0, 0);
    }
    {
      const unsigned short* s0 = vb + hbase + (size_t)(kv0 + vr0) * DH + vhv;
      short8 v0 = *(const short8*)(s0);
      short8 v1 = *(const short8*)(s0 + DH);
      #pragma unroll
      for (int j = 0; j < 8; j++) {
        unsigned int p = ((unsigned short)v0[j]) | (((unsigned int)(unsigned short)v1[j]) << 16);
        *(unsigned int*)&Vt[(vhv + j) * 72 + vr0] = p;
      }
    }
    __syncthreads();

    f32x4 s[2][4];
    #pragma unroll
    for (int kt = 0; kt < 4; kt++) {
      int row = kt * 16 + lr;
      int sw = (row & 7) << 4;
      int byteA = (row * 128 + g * 16) ^ sw;
      int byteB = (row * 128 + 64 + g * 16) ^ sw;
      short8 kA = *(const short8*)((const char*)Kl + byteA);
      short8 kB = *(const short8*)((const char*)Kl + byteB);
      #pragma unroll
      for (int qt = 0; qt < 2; qt++) {
        f32x4 a0 = __builtin_amdgcn_mfma_f32_16x16x32_bf16(kA, qf[qt][0], zero, 0, 0, 0);
        s[qt][kt] = __builtin_amdgcn_mfma_f32_16x16x32_bf16(kB, qf[qt][1], a0, 0, 0, 0);
      }
    }

    float nm[2];
    #pragma unroll
    for (int qt = 0; qt < 2; qt++) {
      f32x4 m01 = s[qt][0];
      #pragma unroll
      for (int kt = 1; kt < 4; kt++) {
        f32x4 sv = s[qt][kt];
        m01[0] = fmaxf(m01[0], sv[0]); m01[1] = fmaxf(m01[1], sv[1]);
        m01[2] = fmaxf(m01[2], sv[2]); m01[3] = fmaxf(m01[3], sv[3]);
      }
      float v = fmaxf(fmaxf(m01[0], m01[1]), fmaxf(m01[2], m01[3]));
      v = fmaxf(v, __shfl_xor(v, 16));
      v = fmaxf(v, __shfl_xor(v, 32));
      nm[qt] = v;
    }

    if (!__all(fmaxf(nm[0] - mrun[0], nm[1] - mrun[1]) <= 8.0f)) {
      const int sb = (lane & 48) + ((lane & 48) >> 2);
      #pragma unroll
      for (int qt = 0; qt < 2; qt++) {
        float m2 = fmaxf(mrun[qt], nm[qt]);
        float cc = exp2f(mrun[qt] - m2);
        mrun[qt] = m2;
        lrun[qt] *= cc;
        float c0r = __shfl(cc, sb + 0);
        float c1r = __shfl(cc, sb + 1);
        float c2r = __shfl(cc, sb + 2);
        float c3r = __shfl(cc, sb + 3);
        #pragma unroll
        for (int dv = 0; dv < 4; dv++) {
          f32x4 a = oacc[qt][dv];
          a[0] *= c0r; a[1] *= c1r; a[2] *= c2r; a[3] *= c3r;
          oacc[qt][dv] = a;
        }
      }
    }

    #pragma unroll
    for (int qt = 0; qt < 2; qt++) {
      float mq = mrun[qt];
      float ls = 0.0f;
      unsigned short* prow = qt ? prow1 : prow0;
      #pragma unroll
      for (int kt = 0; kt < 4; kt++) {
        f32x4 sv = s[qt][kt];
        float p0 = exp2f(sv[0] - mq), p1 = exp2f(sv[1] - mq);
        float p2 = exp2f(sv[2] - mq), p3 = exp2f(sv[3] - mq);
        ls += (p0 + p1) + (p2 + p3);
        u32x2 uu;
        uu.x = cvt_pk_bf16(p0, p1);
        uu.y = cvt_pk_bf16(p2, p3);
        *(u32x2*)(prow + kt * 16 + g * 4) = uu;
      }
      ls += __shfl_xor(ls, 16);
      ls += __shfl_xor(ls, 32);
      lrun[qt] += ls;
    }

    #pragma unroll
    for (int c0 = 0; c0 < 2; c0++) {
      short8 pa0 = *(const short8*)(prow0 + c0 * 32 + g * 8);
      short8 pa1 = *(const short8*)(prow1 + c0 * 32 + g * 8);
      #pragma unroll
      for (int dv = 0; dv < 4; dv++) {
        short8 vf = *(const short8*)&Vt[(dv * 16 + lr) * 72 + c0 * 32 + g * 8];
        oacc[0][dv] = __builtin_amdgcn_mfma_f32_16x16x32_bf16(pa0, vf, oacc[0][dv], 0, 0, 0);
        oacc[1][dv] = __builtin_amdgcn_mfma_f32_16x16x32_bf16(pa1, vf, oacc[1][dv], 0, 0, 0);
      }
    }
  }

  const int b = bh >> 5, h = bh & 31;
  const int sb = (lane & 48) + ((lane & 48) >> 2);
  #pragma unroll
  for (int qt = 0; qt < 2; qt++) {
    float inv = 1.0f / lrun[qt];
    float ir[4];
    ir[0] = __shfl(inv, sb + 0);
    ir[1] = __shfl(inv, sb + 1);
    ir[2] = __shfl(inv, sb + 2);
    ir[3] = __shfl(inv, sb + 3);
    #pragma unroll
    for (int r = 0; r < 4; r++) {
      int ntok = q0 + qt * 16 + g * 4 + r;
      size_t ob = ((size_t)(b * NSEQ + ntok)) * DIMC + h * DH;
      #pragma unroll
      for (int dv = 0; dv < 4; dv++)
        aob[ob + dv * 16 + lr] = f2bf(oacc[qt][dv][r] * ir[r]);
    }
  }
}

// ---------------------------------------------------------------------------
extern "C" void kernel_launch(void* const* d_in, const int* in_sizes, int n_in,
                              void* d_out, int out_size, void* d_ws, size_t ws_size,
                              hipStream_t stream) {
  const float* x     = (const float*)d_in[0];
  const float* freqs = (const float*)d_in[1];
  const float* Wqkv  = (const float*)d_in[2];
  const float* Wout  = (const float*)d_in[3];
  float* out = (float*)d_out;

  char* ws = (char*)d_ws;
  size_t off = 0;
  auto alloc = [&](size_t bytes) {
    void* p = ws + off;
    off += (bytes + 255) & ~(size_t)255;
    return p;
  };
  unsigned short* xb    = (unsigned short*)alloc((size_t)MROWS * DIMC * 2);
  unsigned short* wqkvb = (unsigned short*)alloc((size_t)NQKV * DIMC * 2);
  unsigned short* woutb = (unsigned short*)alloc((size_t)DIMC * DIMC * 2);
  unsigned short* qbuf  = (unsigned short*)alloc((size_t)BHEADS * NSEQ * DH * 2);
  unsigned short* kbuf  = (unsigned short*)alloc((size_t)BHEADS * NSEQ * DH * 2);
  unsigned short* vbuf  = (unsigned short*)alloc((size_t)BHEADS * NSEQ * DH * 2);
  float2* cst           = (float2*)alloc((size_t)NSEQ * DH * sizeof(float2));
  unsigned short* aob   = xb;   // xb dead after gemm1; reuse for attn output

  (void)hipFuncSetAttribute((const void*)gemm256<1>,
      hipFuncAttributeMaxDynamicSharedMemorySize, 131072);
  (void)hipFuncSetAttribute((const void*)gemm256<0>,
      hipFuncAttributeMaxDynamicSharedMemorySize, 131072);

  cvt_bf16<<<2048, 256, 0, stream>>>(x, xb, MROWS * DIMC / 8);
  cvt_bf16<<<2048, 256, 0, stream>>>(Wqkv, wqkvb, NQKV * DIMC / 8);
  cvt_bf16<<<1024, 256, 0, stream>>>(Wout, woutb, DIMC * DIMC / 8);
  build_cs<<<(NSEQ * DH + 255) / 256, 256, 0, stream>>>(freqs, cst, NSEQ * DH);

  gemm256<1><<<dim3(NQKV / 256, MROWS / 256), 512, 131072, stream>>>(
      xb, wqkvb, DIMC, NQKV, nullptr, qbuf, kbuf, vbuf, cst);

  attn_fa<<<dim3(NSEQ / 128, BHEADS), 256, 0, stream>>>(qbuf, kbuf, vbuf, aob);

  gemm256<0><<<dim3(DIMC / 256, MROWS / 256), 512, 131072, stream>>>(
      aob, woutb, DIMC, DIMC, out, nullptr, nullptr, nullptr, nullptr);
}

// Round 8
// 339.062 us; speedup vs baseline: 1.4910x; 1.1030x over previous
//
#include <hip/hip_runtime.h>

#define DIMC 2048
#define NSEQ 2048
#define NBATCH 2
#define NH 32
#define DH 64
#define BHEADS (NBATCH*NH)      // 64
#define MROWS (NBATCH*NSEQ)     // 4096
#define NQKV (3*DIMC)           // 6144

typedef __attribute__((ext_vector_type(8))) short short8;
typedef __attribute__((ext_vector_type(4))) float f32x4;
typedef __attribute__((ext_vector_type(4))) unsigned int uint4v;
typedef __attribute__((ext_vector_type(2))) unsigned int u32x2;

static __device__ __forceinline__ unsigned short f2bf(float f) {
  union { float f; unsigned int u; } v; v.f = f;
  unsigned int r = (v.u + 0x7FFFu + ((v.u >> 16) & 1u)) >> 16;
  return (unsigned short)r;
}

static __device__ __forceinline__ unsigned int cvt_pk_bf16(float lo, float hi) {
  unsigned int r;
  asm("v_cvt_pk_bf16_f32 %0, %1, %2" : "=v"(r) : "v"(lo), "v"(hi));
  return r;
}

#define BAR()    __builtin_amdgcn_s_barrier()
#define FENCE()  asm volatile("" ::: "memory")
#define LGKM0()  asm volatile("s_waitcnt lgkmcnt(0)" ::: "memory")
#define VM(n)    asm volatile("s_waitcnt vmcnt(" #n ")" ::: "memory")

// ---------------- fp32 -> bf16 convert (vectorized, grid-stride) ------------
__global__ __launch_bounds__(256) void cvt_bf16(const float* __restrict__ in,
                                                unsigned short* __restrict__ out,
                                                int n8) {
  int i = blockIdx.x * blockDim.x + threadIdx.x;
  int stride = gridDim.x * blockDim.x;
  for (; i < n8; i += stride) {
    const float4* p = (const float4*)in + (size_t)i * 2;
    float4 a = p[0], b = p[1];
    union { unsigned short u[8]; uint4v v; } o;
    o.u[0] = f2bf(a.x); o.u[1] = f2bf(a.y); o.u[2] = f2bf(a.z); o.u[3] = f2bf(a.w);
    o.u[4] = f2bf(b.x); o.u[5] = f2bf(b.y); o.u[6] = f2bf(b.z); o.u[7] = f2bf(b.w);
    *((uint4v*)out + i) = o.v;
  }
}

// ---------------- cos/sin table --------------------------------------------
__global__ __launch_bounds__(256) void build_cs(const float* __restrict__ freqs,
                                                float2* __restrict__ cs, int n) {
  int i = blockIdx.x * blockDim.x + threadIdx.x;
  if (i < n) { float f = freqs[i]; cs[i] = make_float2(cosf(f), sinf(f)); }
}

// ---------------- GEMM: C[128,256-tile] = A[M,K] * B[N,K]^T -----------------
// 512 thr (8 waves 2Mx4N, 64x64/wave), BK=32, TRIPLE-buffered LDS (3x24KB),
// 1 phase per K-tile: {read 8 frags + stage tile t+2 (3 gloads)} BAR lgkm0
// {16 MFMA} VM(3) BAR. Counted VM(3) keeps t+2's 3 loads in flight, drains
// t+1's (2-tile lead ~2000cyc > HBM latency). WAR: stage(t+2) -> buf((t-1)%3)
// whose last ds_read retired at t-1's lgkm0, >=1 barrier earlier.
// 64B LDS rows: b128 reads are bank-uniform (8 lanes/quad = min) -> no swizzle.
#define QSCALE 0.18033688011112042f   // (1/8) * log2(e)
#define SLOT 24576                     // A 8KB + B 16KB per K-tile

template<int EPI>
__global__ __launch_bounds__(512, 1) void gemm128(
    const unsigned short* __restrict__ A,
    const unsigned short* __restrict__ Bm,
    int Kdim, int Ncols,
    float* __restrict__ Cout,
    unsigned short* __restrict__ qo, unsigned short* __restrict__ ko,
    unsigned short* __restrict__ vo, const float2* __restrict__ cs)
{
  extern __shared__ char Lds[];   // 73728 bytes
  const int t = threadIdx.x;
  const int w = t >> 6, lane = t & 63, lr = lane & 15, g = lane >> 4;
  const int wm = w >> 2, wn = w & 3;

  // XCD-aware bijective swizzle (grid counts are multiples of 8)
  const int nx = gridDim.x;
  int orig = blockIdx.y * nx + blockIdx.x;
  int cpx = (nx * gridDim.y) >> 3;
  int id = (orig & 7) * cpx + (orig >> 3);
  const int m0 = (id / nx) * 128;
  const int n0 = (id % nx) * 256;

  // staging: thread t covers row t>>2, col (t&3)*8 (linear, coalesced)
  const int rowt = t >> 2, colt = (t & 3) * 8;
  const unsigned short* Abase = A + (size_t)(m0 + rowt) * Kdim + colt;
  const unsigned short* Bbase = Bm + (size_t)(n0 + rowt) * Kdim + colt;
  char* dstw = Lds + w * 1024;

  auto STAGE = [&](int sbuf, int T) {
    const unsigned short* sa = Abase + T * 32;
    const unsigned short* sb = Bbase + T * 32;
    __builtin_amdgcn_global_load_lds(
        (const __attribute__((address_space(1))) void*)sa,
        (__attribute__((address_space(3))) void*)(dstw + sbuf), 16, 0, 0);
    __builtin_amdgcn_global_load_lds(
        (const __attribute__((address_space(1))) void*)sb,
        (__attribute__((address_space(3))) void*)(dstw + sbuf + 8192), 16, 0, 0);
    __builtin_amdgcn_global_load_lds(
        (const __attribute__((address_space(1))) void*)(sb + (size_t)128 * Kdim),
        (__attribute__((address_space(3))) void*)(dstw + sbuf + 16384), 16, 0, 0);
  };

  short8 Af[4], Bf[4];
  auto LDAB = [&](int rb) {
    const char* ap = Lds + rb + (wm * 64 + lr) * 64 + g * 16;
    const char* bp = Lds + rb + 8192 + (wn * 64 + lr) * 64 + g * 16;
    #pragma unroll
    for (int m = 0; m < 4; m++) Af[m] = *(const short8*)(ap + m * 1024);
    #pragma unroll
    for (int n = 0; n < 4; n++) Bf[n] = *(const short8*)(bp + n * 1024);
  };

  f32x4 acc[4][4];
  f32x4 zero = {0.0f, 0.0f, 0.0f, 0.0f};
  #pragma unroll
  for (int i = 0; i < 4; i++)
    #pragma unroll
    for (int j = 0; j < 4; j++) acc[i][j] = zero;

  // ---- prologue: stage tiles 0,1; drain tile 0 collectively ----
  STAGE(0, 0); STAGE(SLOT, 1);
  VM(3);
  BAR(); FENCE();

  const int NT = Kdim >> 5;    // 64 K-tiles
  int rb = 0, sb = 2 * SLOT;
  for (int i = 0; i < NT; i++) {
    LDAB(rb);
    if (i + 2 < NT) STAGE(sb, i + 2);
    BAR(); LGKM0();
    __builtin_amdgcn_s_setprio(1);
    #pragma unroll
    for (int m = 0; m < 4; m++)
      #pragma unroll
      for (int n = 0; n < 4; n++)
        acc[m][n] = __builtin_amdgcn_mfma_f32_16x16x32_bf16(Af[m], Bf[n], acc[m][n], 0, 0, 0);
    __builtin_amdgcn_s_setprio(0);
    if (i < NT - 2) { VM(3); } else { VM(0); }
    BAR(); FENCE();
    rb += SLOT; if (rb == 3 * SLOT) rb = 0;
    sb += SLOT; if (sb == 3 * SLOT) sb = 0;
  }

  // ---- epilogue ----
  if (EPI == 0) {
    #pragma unroll
    for (int m = 0; m < 4; m++) {
      #pragma unroll
      for (int r = 0; r < 4; r++) {
        int row = m0 + wm * 64 + m * 16 + g * 4 + r;
        #pragma unroll
        for (int n = 0; n < 4; n++)
          Cout[(size_t)row * Ncols + (n0 + wn * 64 + n * 16 + lr)] = acc[m][n][r];
      }
    }
  } else {
    const int which = n0 >> 11;
    const int head = ((n0 & 2047) + wn * 64) >> 6;
    #pragma unroll
    for (int m = 0; m < 4; m++) {
      #pragma unroll
      for (int r = 0; r < 4; r++) {
        int row = m0 + wm * 64 + m * 16 + g * 4 + r;
        int b = row >> 11, ntok = row & 2047;
        size_t obase = ((size_t)(b * NH + head) * NSEQ + ntok) * DH;
        #pragma unroll
        for (int n = 0; n < 4; n++) {
          int d = n * 16 + lr;
          float val = acc[m][n][r];
          if (which == 2) {
            vo[obase + d] = f2bf(val);
          } else {
            float other = acc[m][n ^ 2][r];
            float2 c2 = cs[ntok * DH + d];
            float rot = (d < 32) ? (val * c2.x - other * c2.y)
                                 : (val * c2.x + other * c2.y);
            if (which == 0) qo[obase + d] = f2bf(rot * QSCALE);
            else            ko[obase + d] = f2bf(rot);
          }
        }
      }
    }
  }
}

// ---------------- flash attention: 4 waves x 32 q, KVBLK=64 -----------------
__global__ __launch_bounds__(256, 4) void attn_fa(
    const unsigned short* __restrict__ qb,
    const unsigned short* __restrict__ kb,
    const unsigned short* __restrict__ vb,
    unsigned short* __restrict__ aob)
{
  __shared__ __align__(16) unsigned short Kl[64 * 64];      // linear, XOR-swizzled content
  __shared__ __align__(16) unsigned short Vt[64 * 72];      // [d][k + pad8]
  __shared__ __align__(16) unsigned short Pl[4][32 * 72];   // per-wave [q][k + pad8]

  const int t = threadIdx.x;
  const int w = t >> 6, lane = t & 63, lr = lane & 15, g = lane >> 4;
  const int bh = blockIdx.y;
  const int q0 = blockIdx.x * 128 + w * 32;
  const size_t hbase = (size_t)bh * NSEQ * DH;

  short8 qf[2][2];
  #pragma unroll
  for (int qt = 0; qt < 2; qt++)
    #pragma unroll
    for (int hf = 0; hf < 2; hf++)
      qf[qt][hf] = *(const short8*)(qb + hbase + (size_t)(q0 + qt * 16 + lr) * DH + hf * 32 + g * 8);

  f32x4 zero = {0.0f, 0.0f, 0.0f, 0.0f};
  f32x4 oacc[2][4];
  #pragma unroll
  for (int qt = 0; qt < 2; qt++)
    #pragma unroll
    for (int dv = 0; dv < 4; dv++) oacc[qt][dv] = zero;
  float mrun[2] = {-1e30f, -1e30f};
  float lrun[2] = {0.0f, 0.0f};

  int kro[2], kdo_[2];
  #pragma unroll
  for (int c = 0; c < 2; c++) {
    int b = w * 2048 + c * 1024 + lane * 16;
    int row = b >> 7;
    int off = b ^ ((row & 7) << 4);
    kro[c] = row;
    kdo_[c] = (off >> 1) & 63;
  }
  const int vr0 = (t & 31) * 2;
  const int vhv = (t >> 5) * 8;

  unsigned short* prow0 = &Pl[w][lr * 72];
  unsigned short* prow1 = &Pl[w][(16 + lr) * 72];

  for (int kv0 = 0; kv0 < NSEQ; kv0 += 64) {
    __syncthreads();
    #pragma unroll
    for (int c = 0; c < 2; c++) {
      const unsigned short* src = kb + hbase + (size_t)(kv0 + kro[c]) * DH + kdo_[c];
      __builtin_amdgcn_global_load_lds(
          (const __attribute__((address_space(1))) void*)src,
          (__attribute__((address_space(3))) void*)(Kl + w * 1024 + c * 512), 16, 0, 0);
    }
    {
      const unsigned short* s0 = vb + hbase + (size_t)(kv0 + vr0) * DH + vhv;
      short8 v0 = *(const short8*)(s0);
      short8 v1 = *(const short8*)(s0 + DH);
      #pragma unroll
      for (int j = 0; j < 8; j++) {
        unsigned int p = ((unsigned short)v0[j]) | (((unsigned int)(unsigned short)v1[j]) << 16);
        *(unsigned int*)&Vt[(vhv + j) * 72 + vr0] = p;
      }
    }
    __syncthreads();

    f32x4 s[2][4];
    #pragma unroll
    for (int kt = 0; kt < 4; kt++) {
      int row = kt * 16 + lr;
      int sw = (row & 7) << 4;
      int byteA = (row * 128 + g * 16) ^ sw;
      int byteB = (row * 128 + 64 + g * 16) ^ sw;
      short8 kA = *(const short8*)((const char*)Kl + byteA);
      short8 kB = *(const short8*)((const char*)Kl + byteB);
      #pragma unroll
      for (int qt = 0; qt < 2; qt++) {
        f32x4 a0 = __builtin_amdgcn_mfma_f32_16x16x32_bf16(kA, qf[qt][0], zero, 0, 0, 0);
        s[qt][kt] = __builtin_amdgcn_mfma_f32_16x16x32_bf16(kB, qf[qt][1], a0, 0, 0, 0);
      }
    }

    float nm[2];
    #pragma unroll
    for (int qt = 0; qt < 2; qt++) {
      f32x4 m01 = s[qt][0];
      #pragma unroll
      for (int kt = 1; kt < 4; kt++) {
        f32x4 sv = s[qt][kt];
        m01[0] = fmaxf(m01[0], sv[0]); m01[1] = fmaxf(m01[1], sv[1]);
        m01[2] = fmaxf(m01[2], sv[2]); m01[3] = fmaxf(m01[3], sv[3]);
      }
      float v = fmaxf(fmaxf(m01[0], m01[1]), fmaxf(m01[2], m01[3]));
      v = fmaxf(v, __shfl_xor(v, 16));
      v = fmaxf(v, __shfl_xor(v, 32));
      nm[qt] = v;
    }

    if (!__all(fmaxf(nm[0] - mrun[0], nm[1] - mrun[1]) <= 8.0f)) {
      const int sb = (lane & 48) + ((lane & 48) >> 2);
      #pragma unroll
      for (int qt = 0; qt < 2; qt++) {
        float m2 = fmaxf(mrun[qt], nm[qt]);
        float cc = exp2f(mrun[qt] - m2);
        mrun[qt] = m2;
        lrun[qt] *= cc;
        float c0r = __shfl(cc, sb + 0);
        float c1r = __shfl(cc, sb + 1);
        float c2r = __shfl(cc, sb + 2);
        float c3r = __shfl(cc, sb + 3);
        #pragma unroll
        for (int dv = 0; dv < 4; dv++) {
          f32x4 a = oacc[qt][dv];
          a[0] *= c0r; a[1] *= c1r; a[2] *= c2r; a[3] *= c3r;
          oacc[qt][dv] = a;
        }
      }
    }

    #pragma unroll
    for (int qt = 0; qt < 2; qt++) {
      float mq = mrun[qt];
      float ls = 0.0f;
      unsigned short* prow = qt ? prow1 : prow0;
      #pragma unroll
      for (int kt = 0; kt < 4; kt++) {
        f32x4 sv = s[qt][kt];
        float p0 = exp2f(sv[0] - mq), p1 = exp2f(sv[1] - mq);
        float p2 = exp2f(sv[2] - mq), p3 = exp2f(sv[3] - mq);
        ls += (p0 + p1) + (p2 + p3);
        u32x2 uu;
        uu.x = cvt_pk_bf16(p0, p1);
        uu.y = cvt_pk_bf16(p2, p3);
        *(u32x2*)(prow + kt * 16 + g * 4) = uu;
      }
      ls += __shfl_xor(ls, 16);
      ls += __shfl_xor(ls, 32);
      lrun[qt] += ls;
    }

    #pragma unroll
    for (int c0 = 0; c0 < 2; c0++) {
      short8 pa0 = *(const short8*)(prow0 + c0 * 32 + g * 8);
      short8 pa1 = *(const short8*)(prow1 + c0 * 32 + g * 8);
      #pragma unroll
      for (int dv = 0; dv < 4; dv++) {
        short8 vf = *(const short8*)&Vt[(dv * 16 + lr) * 72 + c0 * 32 + g * 8];
        oacc[0][dv] = __builtin_amdgcn_mfma_f32_16x16x32_bf16(pa0, vf, oacc[0][dv], 0, 0, 0);
        oacc[1][dv] = __builtin_amdgcn_mfma_f32_16x16x32_bf16(pa1, vf, oacc[1][dv], 0, 0, 0);
      }
    }
  }

  const int b = bh >> 5, h = bh & 31;
  const int sb = (lane & 48) + ((lane & 48) >> 2);
  #pragma unroll
  for (int qt = 0; qt < 2; qt++) {
    float inv = 1.0f / lrun[qt];
    float ir[4];
    ir[0] = __shfl(inv, sb + 0);
    ir[1] = __shfl(inv, sb + 1);
    ir[2] = __shfl(inv, sb + 2);
    ir[3] = __shfl(inv, sb + 3);
    #pragma unroll
    for (int r = 0; r < 4; r++) {
      int ntok = q0 + qt * 16 + g * 4 + r;
      size_t ob = ((size_t)(b * NSEQ + ntok)) * DIMC + h * DH;
      #pragma unroll
      for (int dv = 0; dv < 4; dv++)
        aob[ob + dv * 16 + lr] = f2bf(oacc[qt][dv][r] * ir[r]);
    }
  }
}

// ---------------------------------------------------------------------------
extern "C" void kernel_launch(void* const* d_in, const int* in_sizes, int n_in,
                              void* d_out, int out_size, void* d_ws, size_t ws_size,
                              hipStream_t stream) {
  const float* x     = (const float*)d_in[0];
  const float* freqs = (const float*)d_in[1];
  const float* Wqkv  = (const float*)d_in[2];
  const float* Wout  = (const float*)d_in[3];
  float* out = (float*)d_out;

  char* ws = (char*)d_ws;
  size_t off = 0;
  auto alloc = [&](size_t bytes) {
    void* p = ws + off;
    off += (bytes + 255) & ~(size_t)255;
    return p;
  };
  unsigned short* xb    = (unsigned short*)alloc((size_t)MROWS * DIMC * 2);
  unsigned short* wqkvb = (unsigned short*)alloc((size_t)NQKV * DIMC * 2);
  unsigned short* woutb = (unsigned short*)alloc((size_t)DIMC * DIMC * 2);
  unsigned short* qbuf  = (unsigned short*)alloc((size_t)BHEADS * NSEQ * DH * 2);
  unsigned short* kbuf  = (unsigned short*)alloc((size_t)BHEADS * NSEQ * DH * 2);
  unsigned short* vbuf  = (unsigned short*)alloc((size_t)BHEADS * NSEQ * DH * 2);
  float2* cst           = (float2*)alloc((size_t)NSEQ * DH * sizeof(float2));
  unsigned short* aob   = xb;   // xb dead after gemm1; reuse for attn output

  (void)hipFuncSetAttribute((const void*)gemm128<1>,
      hipFuncAttributeMaxDynamicSharedMemorySize, 3 * SLOT);
  (void)hipFuncSetAttribute((const void*)gemm128<0>,
      hipFuncAttributeMaxDynamicSharedMemorySize, 3 * SLOT);

  cvt_bf16<<<2048, 256, 0, stream>>>(x, xb, MROWS * DIMC / 8);
  cvt_bf16<<<2048, 256, 0, stream>>>(Wqkv, wqkvb, NQKV * DIMC / 8);
  cvt_bf16<<<1024, 256, 0, stream>>>(Wout, woutb, DIMC * DIMC / 8);
  build_cs<<<(NSEQ * DH + 255) / 256, 256, 0, stream>>>(freqs, cst, NSEQ * DH);

  gemm128<1><<<dim3(NQKV / 256, MROWS / 128), 512, 3 * SLOT, stream>>>(
      xb, wqkvb, DIMC, NQKV, nullptr, qbuf, kbuf, vbuf, cst);

  attn_fa<<<dim3(NSEQ / 128, BHEADS), 256, 0, stream>>>(qbuf, kbuf, vbuf, aob);

  gemm128<0><<<dim3(DIMC / 256, MROWS / 128), 512, 3 * SLOT, stream>>>(
      aob, woutb, DIMC, DIMC, out, nullptr, nullptr, nullptr, nullptr);
}